// Round 1
// 100.188 us; speedup vs baseline: 1.0206x; 1.0206x over previous
//
#include <hip/hip_runtime.h>
#include <hip/hip_bf16.h>

typedef __attribute__((ext_vector_type(8))) short short8;
typedef __attribute__((ext_vector_type(4))) float float4v;

__device__ __forceinline__ unsigned short f2bf(float f) {
    // round-to-nearest-even fp32 -> bf16
    unsigned int u = __builtin_bit_cast(unsigned int, f);
    unsigned int lsb = (u >> 16) & 1u;
    u += 0x7fffu + lsb;
    return (unsigned short)(u >> 16);
}

__device__ __forceinline__ unsigned int pack2(float f0, float f1) {
    // round-half-up fp32x2 -> packed bf16x2
    unsigned int u0 = __builtin_bit_cast(unsigned int, f0) + 0x8000u;
    unsigned int u1 = __builtin_bit_cast(unsigned int, f1) + 0x8000u;
    return (u0 >> 16) | (u1 & 0xffff0000u);
}

// ---------------------------------------------------------------------------
// prep (unchanged — proven): LN + projections (MFMA) and woT build.
// b_out stored with XOR-swizzled k-octets. In v9 the swizzled layout is read
// DIRECTLY from global by fused's producers (one full 64B line per row per
// (c,ks) fragment — minimal coalescing), so the layout stays as-is.
// ---------------------------------------------------------------------------
__global__ __launch_bounds__(128) void prep(
    const float* __restrict__ msa, const float* __restrict__ ln_w,
    const float* __restrict__ ln_b, const float* __restrict__ wa,
    const float* __restrict__ ba, const float* __restrict__ wb,
    const float* __restrict__ bb, const float* __restrict__ wo,
    unsigned short* __restrict__ a_out, unsigned short* __restrict__ b_out,
    unsigned short* __restrict__ woT)
{
    const int b = blockIdx.x;
    if (b >= 512) {                       // ---- woT transpose/convert ----
        const int idx = (b - 512) * 128 + threadIdx.x;
        const int hk = idx >> 6, p = idx & 63;
        const int h = hk >> 5, k = hk & 31;
        woT[(size_t)p * 1024 + k * 32 + h] = f2bf(wo[idx]);
        return;
    }

    __shared__ __align__(16) unsigned short xn[2][16 * 72];
    const int n = b >> 1;
    const int w = threadIdx.x >> 6;
    const int lane = threadIdx.x & 63;
    const int s0 = (b & 1) * 32 + w * 16;
    const int sl = lane >> 2, dg = lane & 3;
    const int lm = lane & 15, q = lane >> 4;

    const float* __restrict__ row = msa + ((size_t)((s0 + sl) * 256 + n)) * 64;
    float4 x[4];
    #pragma unroll
    for (int ii = 0; ii < 4; ++ii) x[ii] = *(const float4*)(row + ii * 16 + dg * 4);

    float s = 0.f;
    #pragma unroll
    for (int ii = 0; ii < 4; ++ii) s += (x[ii].x + x[ii].y) + (x[ii].z + x[ii].w);
    s += __shfl_xor(s, 1, 4);
    s += __shfl_xor(s, 2, 4);
    const float mu = s * (1.f / 64.f);

    float v = 0.f;
    #pragma unroll
    for (int ii = 0; ii < 4; ++ii) {
        float a0 = x[ii].x - mu, a1 = x[ii].y - mu, a2 = x[ii].z - mu, a3 = x[ii].w - mu;
        v += (a0 * a0 + a1 * a1) + (a2 * a2 + a3 * a3);
    }
    v += __shfl_xor(v, 1, 4);
    v += __shfl_xor(v, 2, 4);
    const float rs = rsqrtf(v * (1.f / 64.f) + 1e-5f);

    #pragma unroll
    for (int ii = 0; ii < 4; ++ii) {
        const float4 lw = *(const float4*)(ln_w + ii * 16 + dg * 4);
        const float4 lb = *(const float4*)(ln_b + ii * 16 + dg * 4);
        uint2 pk;
        pk.x = pack2((x[ii].x - mu) * rs * lw.x + lb.x, (x[ii].y - mu) * rs * lw.y + lb.y);
        pk.y = pack2((x[ii].z - mu) * rs * lw.z + lb.z, (x[ii].w - mu) * rs * lw.w + lb.w);
        *(uint2*)(&xn[w][sl * 72 + ii * 16 + dg * 4]) = pk;
    }
    __syncthreads();

    short8 afr[2];
    #pragma unroll
    for (int ks = 0; ks < 2; ++ks)
        afr[ks] = *(const short8*)(&xn[w][lm * 72 + ks * 32 + q * 8]);

    float4v acc[4];
    #pragma unroll
    for (int c = 0; c < 4; ++c) acc[c] = (float4v){0.f, 0.f, 0.f, 0.f};
    #pragma unroll
    for (int c = 0; c < 4; ++c) {
        const int hp = c * 16 + lm;
        const float* __restrict__ wsrc = (hp < 32) ? (wa + hp) : (wb + hp - 32);
        #pragma unroll
        for (int ks = 0; ks < 2; ++ks) {
            short8 bfr;
            #pragma unroll
            for (int j = 0; j < 8; ++j)
                bfr[j] = (short)f2bf(wsrc[(ks * 32 + q * 8 + j) * 32]);
            acc[c] = __builtin_amdgcn_mfma_f32_16x16x32_bf16(afr[ks], bfr, acc[c], 0, 0, 0);
        }
    }

    #pragma unroll
    for (int c = 0; c < 4; ++c) {
        const int hp = c * 16 + lm;
        const float bias = (hp < 32) ? ba[hp] : bb[hp - 32];
        const float scale = (hp < 32) ? (1.f / 64.f) : 1.f;  // fold 1/S into a
        uint2 pk;
        pk.x = pack2((acc[c][0] + bias) * scale, (acc[c][1] + bias) * scale);
        pk.y = pack2((acc[c][2] + bias) * scale, (acc[c][3] + bias) * scale);
        const int sbase = s0 + q * 4;
        if (hp < 32) {
            *(uint2*)(a_out + ((size_t)(n * 32 + hp)) * 64 + sbase) = pk;
        } else {
            const int R = n * 32 + (hp - 32);
            const int o = sbase >> 3;
            const int phys = (R << 6) + (((o ^ (R & 7)) << 3) | (sbase & 7));
            *(uint2*)(b_out + phys) = pk;
        }
    }
}

// ---------------------------------------------------------------------------
// fused_opm v9: v8 minus the entire B LDS path.
// v8 model: LDS-bound at ~145 KB/tile (B fill 16 + B read 32 + M 32+32 +
// R 16+16). v9 cuts to 96 KB/tile:
//   producers (waves 0-3): 1x4 col-split — wave w computes ALL 128 A-rows x
//     B-rows [32w, +32): A redundancy lives in registers (af[8][2], free);
//     every B octet is read by exactly ONE (wave,lane,frag), so bf fragments
//     load DIRECTLY from the pre-swizzled global b_swz (dwordx4; the octet
//     XOR keeps each row's 4 q-octets inside one 64B line -> 16 full lines
//     per load). Register double-buffered one tile ahead (bfA/bfB, static
//     ping-pong via 2x-stepped loop). b = 1 MB -> L2/L3-resident; 64 MB
//     aggregate re-read ~2 us of L2 BW, hidden under the previous tile.
//   consumers (waves 4-7): unchanged k-split stage 2 + reduce; fill duty gone.
// ldsB deleted (LDS 143.5 -> 111.5 KB, still 1 block/CU); bar0 removed on
// BOTH paths (18 barriers each). Buffer hazards unchanged: M[t] written (t),
// read (t+1); R[t] written (t+1), read (t+2) — all 1-barrier separated,
// 2-deep buffers give disjoint windows.
// Producer regs: af 64 + acc1 64 + bf 2x16 = 160 + temps (<256, lb(512,2)).
// ---------------------------------------------------------------------------
__global__ __launch_bounds__(512, 2) void fused_opm(
    const unsigned short* __restrict__ a_b, const unsigned short* __restrict__ b_swz,
    const unsigned short* __restrict__ woT, const float* __restrict__ bo,
    float* __restrict__ out)
{
    __shared__ __align__(16) unsigned short ldsM[2][16 * 1272]; // 79.5 KB
    __shared__ __align__(16) float ldsR[2][4096];               // 32 KB

    const int b = blockIdx.x;
    const int bi = b >> 2;
    const int bj0 = (b & 3) << 4;        // 16 tiles per block
    const int wv = threadIdx.x >> 6;
    const int lane = threadIdx.x & 63;
    const int lm = lane & 15, q = lane >> 4;

    if (wv < 4) {
        // ============ PRODUCERS: stage 1 (1x4 col-split, B from global) ============
        const int w = wv;                 // j_loc = w

        short8 af[8][2];                  // all 128 A-rows: bi*128 + r*16 + lm
        #pragma unroll
        for (int r = 0; r < 8; ++r)
            #pragma unroll
            for (int ks = 0; ks < 2; ++ks)
                af[r][ks] = *(const short8*)(a_b + ((size_t)(bi * 128 + r * 16 + lm)) * 64 + ks * 32 + q * 8);

        short8 bfA[2][2], bfB[2][2];      // register double-buffer, one tile ahead
        auto loadbf = [&](short8 (&dst)[2][2], int tt) {
            const unsigned short* __restrict__ Bt = b_swz + (size_t)(bj0 + tt) * 8192;
            #pragma unroll
            for (int c = 0; c < 2; ++c)
                #pragma unroll
                for (int ks = 0; ks < 2; ++ks) {
                    const int rrow = w * 32 + c * 16 + lm;
                    const int o = ks * 4 + q;             // k-octet
                    dst[c][ks] = *(const short8*)(Bt + (rrow << 6) + ((o ^ (rrow & 7)) << 3));
                }
        };
        auto step = [&](short8 (&cur)[2][2], short8 (&nxt)[2][2], int t) {
            if (t + 1 < 16) loadbf(nxt, t + 1);           // issue before MFMAs
            if (t < 16) {
                unsigned short* __restrict__ M = ldsM[t & 1];
                float4v acc1[8][2];
                #pragma unroll
                for (int r = 0; r < 8; ++r)
                    #pragma unroll
                    for (int c = 0; c < 2; ++c) acc1[r][c] = (float4v){0.f, 0.f, 0.f, 0.f};
                #pragma unroll
                for (int c = 0; c < 2; ++c)
                    #pragma unroll
                    for (int ks = 0; ks < 2; ++ks)
                        #pragma unroll
                        for (int r = 0; r < 8; ++r)
                            acc1[r][c] = __builtin_amdgcn_mfma_f32_16x16x32_bf16(af[r][ks], cur[c][ks], acc1[r][c], 0, 0, 0);

                // C row = r*16 + q*4+e -> i_loc = r>>1, h = (r&1)*16 + q*4+e
                // C col = w*32 + c*16 + lm -> j_loc = w, k = c*16 + lm
                #pragma unroll
                for (int r = 0; r < 8; ++r)
                    #pragma unroll
                    for (int c = 0; c < 2; ++c) {
                        const int pair = (r >> 1) * 4 + w;
                        const int k = (c << 4) + lm;
                        const int h0 = ((r & 1) << 4) + q * 4;
                        uint2 pk;
                        pk.x = pack2(acc1[r][c][0], acc1[r][c][1]);
                        pk.y = pack2(acc1[r][c][2], acc1[r][c][3]);
                        *(uint2*)(M + pair * 1272 + k * 40 + h0) = pk;
                    }
            }
        };

        loadbf(bfA, 0);
        for (int t = 0; t < 18; t += 2) { // static ping-pong parity
            step(bfA, bfB, t);
            __syncthreads();              // bar(t+1)
            step(bfB, bfA, t + 1);
            __syncthreads();              // bar(t+2)
        }
    } else {
        // ============ CONSUMERS: k-split stage 2 + reduce (no fill duty) ============
        const int cw = wv - 4;            // k-slice [cw*8, cw*8+8), reduce p-tile cw

        short8 wf[4][8];                  // woT rows p = mt*16+lm, k = cw*8+ks
        #pragma unroll
        for (int mt = 0; mt < 4; ++mt)
            #pragma unroll
            for (int ks = 0; ks < 8; ++ks)
                wf[mt][ks] = *(const short8*)(woT + ((size_t)(mt * 16 + lm)) * 1024 + (cw * 8 + ks) * 32 + q * 8);

        const float4 bo4 = *(const float4*)(bo + cw * 16 + q * 4);
        const int i = bi * 4 + (lm >> 2);
        const int jb = lm & 3;

        for (int t = 0; t < 18; ++t) {
            if (t >= 1 && t <= 16) {      // stage2(t-1): partials for tile t-1
                const int tt = t - 1;
                const unsigned short* __restrict__ M = ldsM[tt & 1];
                float4v acc2[4];
                #pragma unroll
                for (int mt = 0; mt < 4; ++mt) acc2[mt] = (float4v){0.f, 0.f, 0.f, 0.f};
                #pragma unroll
                for (int ks = 0; ks < 8; ++ks) {
                    const short8 mf = *(const short8*)(M + lm * 1272 + (cw * 8 + ks) * 40 + q * 8);
                    #pragma unroll
                    for (int mt = 0; mt < 4; ++mt)
                        acc2[mt] = __builtin_amdgcn_mfma_f32_16x16x32_bf16(wf[mt][ks], mf, acc2[mt], 0, 0, 0);
                }
                float* __restrict__ R = ldsR[tt & 1];
                #pragma unroll
                for (int mt = 0; mt < 4; ++mt)
                    *(float4v*)(&R[((cw * 4 + mt) << 8) + (lane << 2)]) = acc2[mt];
            }

            if (t >= 2) {                 // reduce(t-2): p-tile cw, all k-slices
                const int tt = t - 2;
                const float* __restrict__ R = ldsR[tt & 1];
                float4v sum = *(const float4v*)(&R[(cw << 8) + (lane << 2)]);
                #pragma unroll
                for (int kh = 1; kh < 4; ++kh)
                    sum += *(const float4v*)(&R[((kh * 4 + cw) << 8) + (lane << 2)]);
                const int j = (bj0 + tt) * 4 + jb;
                float4 o;
                o.x = sum[0] + bo4.x;
                o.y = sum[1] + bo4.y;
                o.z = sum[2] + bo4.z;
                o.w = sum[3] + bo4.w;
                *(float4*)(out + ((size_t)(i * 256 + j)) * 64 + cw * 16 + q * 4) = o;
            }
            __syncthreads();              // bar(t+1)
        }
    }
}

// ---------------------------------------------------------------------------
extern "C" void kernel_launch(void* const* d_in, const int* in_sizes, int n_in,
                              void* d_out, int out_size, void* d_ws, size_t ws_size,
                              hipStream_t stream) {
    const float* msa  = (const float*)d_in[0];
    const float* ln_w = (const float*)d_in[1];
    const float* ln_b = (const float*)d_in[2];
    const float* wa   = (const float*)d_in[3];
    const float* ba   = (const float*)d_in[4];
    const float* wb   = (const float*)d_in[5];
    const float* bb   = (const float*)d_in[6];
    const float* wo   = (const float*)d_in[7];
    const float* bo   = (const float*)d_in[8];
    float* out = (float*)d_out;

    // workspace (bf16): a (1 MB) | b (1 MB, octet-swizzled) | woT (128 KB)
    unsigned short* a_ws = (unsigned short*)d_ws;
    unsigned short* b_ws = a_ws + 256 * 32 * 64;
    unsigned short* woT  = b_ws + 256 * 32 * 64;

    prep<<<1024, 128, 0, stream>>>(msa, ln_w, ln_b, wa, ba, wb, bb, wo, a_ws, b_ws, woT);
    fused_opm<<<256, 512, 0, stream>>>(a_ws, b_ws, woT, bo, out);
}

// Round 2
// 98.992 us; speedup vs baseline: 1.0329x; 1.0121x over previous
//
#include <hip/hip_runtime.h>
#include <hip/hip_bf16.h>

typedef __attribute__((ext_vector_type(8))) short short8;
typedef __attribute__((ext_vector_type(4))) float float4v;
typedef __attribute__((ext_vector_type(16))) float f32x16;

__device__ __forceinline__ unsigned short f2bf(float f) {
    // round-to-nearest-even fp32 -> bf16
    unsigned int u = __builtin_bit_cast(unsigned int, f);
    unsigned int lsb = (u >> 16) & 1u;
    u += 0x7fffu + lsb;
    return (unsigned short)(u >> 16);
}

__device__ __forceinline__ unsigned int pack2(float f0, float f1) {
    // round-half-up fp32x2 -> packed bf16x2
    unsigned int u0 = __builtin_bit_cast(unsigned int, f0) + 0x8000u;
    unsigned int u1 = __builtin_bit_cast(unsigned int, f1) + 0x8000u;
    return (u0 >> 16) | (u1 & 0xffff0000u);
}

// ---------------------------------------------------------------------------
// prep v10: LN + projections (MFMA) and woT build. b_out now stored PLAIN
// (v8's XOR-octet swizzle removed — it served global_load_lds, which v9
// deleted) in layout b3[octet o][R=global b-row][8 shorts]: fused's 32x32
// producer B-loads become two contiguous 512B blocks per instruction.
// ---------------------------------------------------------------------------
__global__ __launch_bounds__(128) void prep(
    const float* __restrict__ msa, const float* __restrict__ ln_w,
    const float* __restrict__ ln_b, const float* __restrict__ wa,
    const float* __restrict__ ba, const float* __restrict__ wb,
    const float* __restrict__ bb, const float* __restrict__ wo,
    unsigned short* __restrict__ a_out, unsigned short* __restrict__ b_out,
    unsigned short* __restrict__ woT)
{
    const int b = blockIdx.x;
    if (b >= 512) {                       // ---- woT transpose/convert ----
        const int idx = (b - 512) * 128 + threadIdx.x;
        const int hk = idx >> 6, p = idx & 63;
        const int h = hk >> 5, k = hk & 31;
        woT[(size_t)p * 1024 + k * 32 + h] = f2bf(wo[idx]);
        return;
    }

    __shared__ __align__(16) unsigned short xn[2][16 * 72];
    const int n = b >> 1;
    const int w = threadIdx.x >> 6;
    const int lane = threadIdx.x & 63;
    const int s0 = (b & 1) * 32 + w * 16;
    const int sl = lane >> 2, dg = lane & 3;
    const int lm = lane & 15, q = lane >> 4;

    const float* __restrict__ row = msa + ((size_t)((s0 + sl) * 256 + n)) * 64;
    float4 x[4];
    #pragma unroll
    for (int ii = 0; ii < 4; ++ii) x[ii] = *(const float4*)(row + ii * 16 + dg * 4);

    float s = 0.f;
    #pragma unroll
    for (int ii = 0; ii < 4; ++ii) s += (x[ii].x + x[ii].y) + (x[ii].z + x[ii].w);
    s += __shfl_xor(s, 1, 4);
    s += __shfl_xor(s, 2, 4);
    const float mu = s * (1.f / 64.f);

    float v = 0.f;
    #pragma unroll
    for (int ii = 0; ii < 4; ++ii) {
        float a0 = x[ii].x - mu, a1 = x[ii].y - mu, a2 = x[ii].z - mu, a3 = x[ii].w - mu;
        v += (a0 * a0 + a1 * a1) + (a2 * a2 + a3 * a3);
    }
    v += __shfl_xor(v, 1, 4);
    v += __shfl_xor(v, 2, 4);
    const float rs = rsqrtf(v * (1.f / 64.f) + 1e-5f);

    #pragma unroll
    for (int ii = 0; ii < 4; ++ii) {
        const float4 lw = *(const float4*)(ln_w + ii * 16 + dg * 4);
        const float4 lb = *(const float4*)(ln_b + ii * 16 + dg * 4);
        uint2 pk;
        pk.x = pack2((x[ii].x - mu) * rs * lw.x + lb.x, (x[ii].y - mu) * rs * lw.y + lb.y);
        pk.y = pack2((x[ii].z - mu) * rs * lw.z + lb.z, (x[ii].w - mu) * rs * lw.w + lb.w);
        *(uint2*)(&xn[w][sl * 72 + ii * 16 + dg * 4]) = pk;
    }
    __syncthreads();

    short8 afr[2];
    #pragma unroll
    for (int ks = 0; ks < 2; ++ks)
        afr[ks] = *(const short8*)(&xn[w][lm * 72 + ks * 32 + q * 8]);

    float4v acc[4];
    #pragma unroll
    for (int c = 0; c < 4; ++c) acc[c] = (float4v){0.f, 0.f, 0.f, 0.f};
    #pragma unroll
    for (int c = 0; c < 4; ++c) {
        const int hp = c * 16 + lm;
        const float* __restrict__ wsrc = (hp < 32) ? (wa + hp) : (wb + hp - 32);
        #pragma unroll
        for (int ks = 0; ks < 2; ++ks) {
            short8 bfr;
            #pragma unroll
            for (int j = 0; j < 8; ++j)
                bfr[j] = (short)f2bf(wsrc[(ks * 32 + q * 8 + j) * 32]);
            acc[c] = __builtin_amdgcn_mfma_f32_16x16x32_bf16(afr[ks], bfr, acc[c], 0, 0, 0);
        }
    }

    #pragma unroll
    for (int c = 0; c < 4; ++c) {
        const int hp = c * 16 + lm;
        const float bias = (hp < 32) ? ba[hp] : bb[hp - 32];
        const float scale = (hp < 32) ? (1.f / 64.f) : 1.f;  // fold 1/S into a
        uint2 pk;
        pk.x = pack2((acc[c][0] + bias) * scale, (acc[c][1] + bias) * scale);
        pk.y = pack2((acc[c][2] + bias) * scale, (acc[c][3] + bias) * scale);
        const int sbase = s0 + q * 4;
        if (hp < 32) {
            *(uint2*)(a_out + ((size_t)(n * 32 + hp)) * 64 + sbase) = pk;
        } else {
            // b3[o][R][8]: o = s-octet, R = global b-row; uint2 = half an octet
            const int R = n * 32 + (hp - 32);
            const int o = sbase >> 3;
            *(uint2*)(b_out + (size_t)o * 65536 + R * 8 + (sbase & 7)) = pk;
        }
    }
}

// ---------------------------------------------------------------------------
// fused_opm v10: v9 with stage 1 moved to mfma_f32_32x32x16_bf16.
// v9 post-mortem: fused ~9.4 us sits near its 16x16 MFMA floor (per SIMD per
// tile: producer 32 mfma x19.4 = 621 cyc + consumer 621), LDS (96 KB/tile)
// is no longer binding. 32x32x16 runs at 2495 vs 2075 TF -> producer tile
// cost 621 -> 16 x 32.3 = 516 cyc/SIMD (-17%).
//   producers (waves 0-3): wave w = all 128 A-rows x B-rows [32w,+32).
//     af[rf][ks]: A row = bi*128+rf*32+(lane&31), k(s) = ks*16+(lane>>5)*8.
//     bf[ks] from plain b3 layout: two contiguous 512B blocks per load.
//     acc1[rf] f32x16; C: col(lane&31)=k, row=(reg&3)+8*(reg>>2)+4*(lane>>5)
//     = h, pair = rf*4+w -> same M[pair][k][h] container as v9 (write stays
//     at the 4-access/bank LDS minimum). Regs: af 64 + acc 64 + bf 2x16 = 160.
//   consumers (waves 4-7): UNCHANGED (16x16 k-split stage 2 + reduce).
//     (32x32 stage 2 would waste half its B-cols at 16 pairs/tile; needs
//     2-tile batching + 3-deep M — next step if consumer chain is critical.)
// Pipeline/barriers/buffers identical to v9.
// ---------------------------------------------------------------------------
__global__ __launch_bounds__(512, 2) void fused_opm(
    const unsigned short* __restrict__ a_b, const unsigned short* __restrict__ b_swz,
    const unsigned short* __restrict__ woT, const float* __restrict__ bo,
    float* __restrict__ out)
{
    __shared__ __align__(16) unsigned short ldsM[2][16 * 1272]; // 79.5 KB
    __shared__ __align__(16) float ldsR[2][4096];               // 32 KB

    const int b = blockIdx.x;
    const int bi = b >> 2;
    const int bj0 = (b & 3) << 4;        // 16 tiles per block
    const int wv = threadIdx.x >> 6;
    const int lane = threadIdx.x & 63;
    const int lm = lane & 15, q = lane >> 4;

    if (wv < 4) {
        // ========= PRODUCERS: stage 1 (32x32x16, B from plain-layout global) =========
        const int w = wv;                 // B-row slice [32w, +32)
        const int l31 = lane & 31, h5 = lane >> 5;

        short8 af[4][4];                  // [rf: row block][ks: s-step]
        #pragma unroll
        for (int rf = 0; rf < 4; ++rf)
            #pragma unroll
            for (int ks = 0; ks < 4; ++ks)
                af[rf][ks] = *(const short8*)(a_b + ((size_t)(bi * 128 + rf * 32 + l31)) * 64 + ks * 16 + h5 * 8);

        short8 bfA[4], bfB[4];            // register double-buffer, one tile ahead
        auto loadbf = [&](short8 (&dst)[4], int tt) {
            const int Rbase = (bj0 + tt) * 128 + w * 32 + l31;
            #pragma unroll
            for (int ks = 0; ks < 4; ++ks) {
                const int o = ks * 2 + h5;                // s-octet
                dst[ks] = *(const short8*)(b_swz + (size_t)o * 65536 + (size_t)Rbase * 8);
            }
        };
        auto step = [&](short8 (&cur)[4], short8 (&nxt)[4], int t) {
            if (t + 1 < 16) loadbf(nxt, t + 1);           // issue before MFMAs
            if (t < 16) {
                unsigned short* __restrict__ M = ldsM[t & 1];
                f32x16 acc1[4];
                #pragma unroll
                for (int rf = 0; rf < 4; ++rf)
                    #pragma unroll
                    for (int e = 0; e < 16; ++e) acc1[rf][e] = 0.f;
                #pragma unroll
                for (int ks = 0; ks < 4; ++ks)
                    #pragma unroll
                    for (int rf = 0; rf < 4; ++rf)
                        acc1[rf] = __builtin_amdgcn_mfma_f32_32x32x16_bf16(af[rf][ks], cur[ks], acc1[rf], 0, 0, 0);

                // C col = l31 -> k; C row = (reg&3) + 8*(reg>>2) + 4*h5 -> h;
                // i_loc = rf, j_loc = w -> pair = rf*4 + w.
                #pragma unroll
                for (int rf = 0; rf < 4; ++rf)
                    #pragma unroll
                    for (int g = 0; g < 4; ++g) {
                        uint2 pk;
                        pk.x = pack2(acc1[rf][4 * g + 0], acc1[rf][4 * g + 1]);
                        pk.y = pack2(acc1[rf][4 * g + 2], acc1[rf][4 * g + 3]);
                        *(uint2*)(M + (rf * 4 + w) * 1272 + l31 * 40 + 8 * g + 4 * h5) = pk;
                    }
            }
        };

        loadbf(bfA, 0);
        for (int t = 0; t < 18; t += 2) { // static ping-pong parity
            step(bfA, bfB, t);
            __syncthreads();              // bar(t+1)
            step(bfB, bfA, t + 1);
            __syncthreads();              // bar(t+2)
        }
    } else {
        // ============ CONSUMERS: k-split stage 2 + reduce (unchanged) ============
        const int cw = wv - 4;            // k-slice [cw*8, cw*8+8), reduce p-tile cw

        short8 wf[4][8];                  // woT rows p = mt*16+lm, k = cw*8+ks
        #pragma unroll
        for (int mt = 0; mt < 4; ++mt)
            #pragma unroll
            for (int ks = 0; ks < 8; ++ks)
                wf[mt][ks] = *(const short8*)(woT + ((size_t)(mt * 16 + lm)) * 1024 + (cw * 8 + ks) * 32 + q * 8);

        const float4 bo4 = *(const float4*)(bo + cw * 16 + q * 4);
        const int i = bi * 4 + (lm >> 2);
        const int jb = lm & 3;

        for (int t = 0; t < 18; ++t) {
            if (t >= 1 && t <= 16) {      // stage2(t-1): partials for tile t-1
                const int tt = t - 1;
                const unsigned short* __restrict__ M = ldsM[tt & 1];
                float4v acc2[4];
                #pragma unroll
                for (int mt = 0; mt < 4; ++mt) acc2[mt] = (float4v){0.f, 0.f, 0.f, 0.f};
                #pragma unroll
                for (int ks = 0; ks < 8; ++ks) {
                    const short8 mf = *(const short8*)(M + lm * 1272 + (cw * 8 + ks) * 40 + q * 8);
                    #pragma unroll
                    for (int mt = 0; mt < 4; ++mt)
                        acc2[mt] = __builtin_amdgcn_mfma_f32_16x16x32_bf16(wf[mt][ks], mf, acc2[mt], 0, 0, 0);
                }
                float* __restrict__ R = ldsR[tt & 1];
                #pragma unroll
                for (int mt = 0; mt < 4; ++mt)
                    *(float4v*)(&R[((cw * 4 + mt) << 8) + (lane << 2)]) = acc2[mt];
            }

            if (t >= 2) {                 // reduce(t-2): p-tile cw, all k-slices
                const int tt = t - 2;
                const float* __restrict__ R = ldsR[tt & 1];
                float4v sum = *(const float4v*)(&R[(cw << 8) + (lane << 2)]);
                #pragma unroll
                for (int kh = 1; kh < 4; ++kh)
                    sum += *(const float4v*)(&R[((kh * 4 + cw) << 8) + (lane << 2)]);
                const int j = (bj0 + tt) * 4 + jb;
                float4 o;
                o.x = sum[0] + bo4.x;
                o.y = sum[1] + bo4.y;
                o.z = sum[2] + bo4.z;
                o.w = sum[3] + bo4.w;
                *(float4*)(out + ((size_t)(i * 256 + j)) * 64 + cw * 16 + q * 4) = o;
            }
            __syncthreads();              // bar(t+1)
        }
    }
}

// ---------------------------------------------------------------------------
extern "C" void kernel_launch(void* const* d_in, const int* in_sizes, int n_in,
                              void* d_out, int out_size, void* d_ws, size_t ws_size,
                              hipStream_t stream) {
    const float* msa  = (const float*)d_in[0];
    const float* ln_w = (const float*)d_in[1];
    const float* ln_b = (const float*)d_in[2];
    const float* wa   = (const float*)d_in[3];
    const float* ba   = (const float*)d_in[4];
    const float* wb   = (const float*)d_in[5];
    const float* bb   = (const float*)d_in[6];
    const float* wo   = (const float*)d_in[7];
    const float* bo   = (const float*)d_in[8];
    float* out = (float*)d_out;

    // workspace (bf16): a (1 MB) | b3 (1 MB, [octet][row] layout) | woT (128 KB)
    unsigned short* a_ws = (unsigned short*)d_ws;
    unsigned short* b_ws = a_ws + 256 * 32 * 64;
    unsigned short* woT  = b_ws + 256 * 32 * 64;

    prep<<<1024, 128, 0, stream>>>(msa, ln_w, ln_b, wa, ba, wb, bb, wo, a_ws, b_ws, woT);
    fused_opm<<<256, 512, 0, stream>>>(a_ws, b_ws, woT, bo, out);
}